// Round 11
// baseline (74.235 us; speedup 1.0000x reference)
//
#include <hip/hip_runtime.h>

// UnionRGCNLayer, fused MFMA version (single-pass 1024-thread gather):
//   k_pack: zero gcnt + pack Whp into MFMA fragment order
//   k_comb: blocks [0,nBB):        bin 8k edges each into per-dst-block buckets
//           blocks [nBB,nBB+nPB):  pack [Wn;Lw;Ew]->Wfrag, emb->emb16
//           blocks [nBB+nPB,..):   t = [h|pos] @ W_hp (bf16 MFMA, M=64)
//   k_fused per 32-row block (1024 thr, 16 waves):
//     phase0: read own bucket (coalesced), re-bin to per-dst LDS lists (LDS atomics)
//     phase1: 32 streams (16 waves x 2 halves) = 32 nodes, ONE pass (no serial p-loop);
//             16-lane groups, uint4 row loads, sel-masked uniform control flow
//     phase2: out = relu([x0 | f*h | (1-f)*h] @ [Wn;Lw;Ew]); 16 waves = 2x8 tiles
//     pos:    out_pos = relu(pos + pos @ (f ? Lwp : Ewp))
// MFMA packing convention (consistent A/B; k-permutation cancels):
//   A: lane l elem j -> A[l&15][(l>>4)*8+j];  B: lane l elem j -> B[(l>>4)*8+j][l&15]
//   C/D (m89-verified): lane l reg r -> D[(l>>4)*4+r][l&15]

#define BS 1536        // bucket capacity (mean 512, 22 sigma headroom)
#define CAP2 48        // per-dst list cap (Poisson(16): P(>48) ~ 1e-12)
#define CH 8192        // edges per bin block

typedef __bf16 bf16x8 __attribute__((ext_vector_type(8)));
typedef float f32x4 __attribute__((ext_vector_type(4)));
typedef unsigned short u16x4 __attribute__((ext_vector_type(4)));

__device__ inline unsigned short f2bf(float f) {
    unsigned u = __float_as_uint(f);
    u += 0x7fffu + ((u >> 16) & 1u);
    return (unsigned short)(u >> 16);
}
__device__ inline float bflo(unsigned u) { return __uint_as_float(u << 16); }
__device__ inline float bfhi(unsigned u) { return __uint_as_float(u & 0xffff0000u); }

// ---------------- k_pack: zero gcnt + Whp fragment packing ----------------
__global__ __launch_bounds__(256) void k_pack(const float* __restrict__ Whp,
                                              int* __restrict__ gcnt,
                                              unsigned short* __restrict__ Whpfrag,
                                              int nbkt) {
    const int gid = blockIdx.x * blockDim.x + threadIdx.x;
    const int gs = gridDim.x * blockDim.x;
    for (int i = gid; i < nbkt; i += gs) gcnt[i] = 0;
    for (int i = gid; i < 16384; i += gs) {  // Whp rows 0..127 -> fragment order
        int j = i & 7, l = (i >> 3) & 63, nt = (i >> 9) & 7, c = i >> 12;
        int k = c * 32 + ((l >> 4) << 3) + j;
        int n = nt * 16 + (l & 15);
        Whpfrag[i] = f2bf(Whp[k * 128 + n]);
    }
}

// ---------------- k_comb: bin (first) + pack + t-GEMM (M=64) ----------------
__global__ __launch_bounds__(512) void k_comb(const float* __restrict__ h,
                                              const float* __restrict__ pos,
                                              const float* __restrict__ Whp,
                                              const unsigned short* __restrict__ Whpfrag,
                                              unsigned short* __restrict__ t,
                                              const int* __restrict__ esrc,
                                              const int* __restrict__ edst,
                                              const int* __restrict__ etyp, int E,
                                              int* __restrict__ gcnt,
                                              unsigned* __restrict__ gbuf,
                                              const float* __restrict__ emb, int embN,
                                              const float* __restrict__ Wn,
                                              const float* __restrict__ Lw,
                                              const float* __restrict__ Ew,
                                              unsigned short* __restrict__ emb16,
                                              unsigned short* __restrict__ Wfrag,
                                              int nBB, int nPB,
                                              int nbkt, int N) {
    __shared__ unsigned short hsh[64][136];   // GEMM tile; aliased by bin path
    __shared__ float WpS[3][128];
    __shared__ float posS[64][4];
    const int tid = threadIdx.x;

    if (blockIdx.x < nBB) {
        // ---- bin block: two-pass LDS-count binning of CH edges, int4-vectorized ----
        int* lcnt = reinterpret_cast<int*>(&hsh[0][0]);   // nbkt ints
        int* lbase = lcnt + 1280;                         // nbkt ints
        const int e0 = blockIdx.x * CH;
        const int eN = min(E - e0, CH);
        for (int i = tid; i < nbkt; i += 512) lcnt[i] = 0;
        __syncthreads();
        // pass A: histogram (4 edges per thread per sweep)
        for (int base = tid * 4; base < eN; base += 2048) {
            if (base + 3 < eN) {
                int4 d4 = *reinterpret_cast<const int4*>(&edst[e0 + base]);
                atomicAdd(&lcnt[d4.x >> 5], 1);
                atomicAdd(&lcnt[d4.y >> 5], 1);
                atomicAdd(&lcnt[d4.z >> 5], 1);
                atomicAdd(&lcnt[d4.w >> 5], 1);
            } else {
                for (int k = 0; k < 4 && base + k < eN; k++)
                    atomicAdd(&lcnt[edst[e0 + base + k] >> 5], 1);
            }
        }
        __syncthreads();
        // reserve contiguous runs: 1 global atomic per (bucket,block)
        for (int i = tid; i < nbkt; i += 512) {
            int c = lcnt[i];
            lbase[i] = c ? atomicAdd(&gcnt[i], c) : 0;
        }
        __syncthreads();
        for (int i = tid; i < nbkt; i += 512) lcnt[i] = 0;
        __syncthreads();
        // pass B: write runs (3 int4 loads in flight, 4 independent atomic+store)
        for (int base = tid * 4; base < eN; base += 2048) {
            if (base + 3 < eN) {
                int4 d4 = *reinterpret_cast<const int4*>(&edst[e0 + base]);
                int4 s4 = *reinterpret_cast<const int4*>(&esrc[e0 + base]);
                int4 t4 = *reinterpret_cast<const int4*>(&etyp[e0 + base]);
                int dd[4] = {d4.x, d4.y, d4.z, d4.w};
                int ss[4] = {s4.x, s4.y, s4.z, s4.w};
                int tt[4] = {t4.x, t4.y, t4.z, t4.w};
#pragma unroll
                for (int k = 0; k < 4; k++) {
                    int b = dd[k] >> 5;
                    unsigned val = (unsigned)(dd[k] & 31) | ((unsigned)ss[k] << 5)
                                 | ((unsigned)tt[k] << 21);
                    int off = atomicAdd(&lcnt[b], 1);
                    gbuf[(size_t)b * BS + min(lbase[b] + off, BS - 1)] = val;
                }
            } else {
                for (int k = 0; k < 4 && base + k < eN; k++) {
                    int d = edst[e0 + base + k];
                    int b = d >> 5;
                    unsigned val = (unsigned)(d & 31) | ((unsigned)esrc[e0 + base + k] << 5)
                                 | ((unsigned)etyp[e0 + base + k] << 21);
                    int off = atomicAdd(&lcnt[b], 1);
                    gbuf[(size_t)b * BS + min(lbase[b] + off, BS - 1)] = val;
                }
            }
        }
        return;
    }

    if (blockIdx.x < nBB + nPB) {
        // packing blocks: Wfrag + emb16 (consumed only by k_fused)
        const int base = (blockIdx.x - nBB) * 512 + tid;
        const int gs = nPB * 512;
        for (int i = base; i < 49152; i += gs) {
            int j = i & 7, l = (i >> 3) & 63, nt = (i >> 9) & 7, c = i >> 12;
            int k = c * 32 + ((l >> 4) << 3) + j;
            int n = nt * 16 + (l & 15);
            float v = (k < 128) ? Wn[k * 128 + n]
                    : (k < 256) ? Lw[(k - 128) * 128 + n]
                                : Ew[(k - 256) * 128 + n];
            Wfrag[i] = f2bf(v);
        }
        for (int i = base; i < embN; i += gs) emb16[i] = f2bf(emb[i]);
        return;
    }

    // ---- t-GEMM block ----
    const int rbase = (blockIdx.x - nBB - nPB) * 64;
    const int w = tid >> 6, l = tid & 63;
    for (int i = tid; i < 384; i += 512) WpS[i >> 7][i & 127] = Whp[128 * 128 + i];
    if (tid < 192) {
        int r = tid / 3, j = tid % 3;
        int row = rbase + r;
        posS[r][j] = (row < N) ? pos[(size_t)row * 3 + j] : 0.f;
    }
#pragma unroll
    for (int it = 0; it < 4; it++) {  // stage 64x128 h tile as bf16
        int qid = tid + it * 512;
        int rr = qid >> 5, cq = qid & 31;
        int row = rbase + rr;
        u16x4 v = {0, 0, 0, 0};
        if (row < N) {
            float4 a = *reinterpret_cast<const float4*>(h + (size_t)row * 128 + cq * 4);
            v[0] = f2bf(a.x); v[1] = f2bf(a.y); v[2] = f2bf(a.z); v[3] = f2bf(a.w);
        }
        *reinterpret_cast<u16x4*>(&hsh[rr][cq * 4]) = v;
    }
    __syncthreads();

    f32x4 acc[4];
#pragma unroll
    for (int i = 0; i < 4; i++) acc[i] = (f32x4){0.f, 0.f, 0.f, 0.f};
    const int rt = w >> 1, ch = w & 1;   // 4 row-tiles x 2 col-halves
#pragma unroll
    for (int c = 0; c < 4; c++) {
        bf16x8 a = *reinterpret_cast<const bf16x8*>(&hsh[rt * 16 + (l & 15)][c * 32 + (l >> 4) * 8]);
        const bf16x8* Bp = reinterpret_cast<const bf16x8*>(Whpfrag) + (size_t)c * 512;
#pragma unroll
        for (int n2 = 0; n2 < 4; n2++) {
            bf16x8 b = Bp[(ch * 4 + n2) * 64 + l];
            acc[n2] = __builtin_amdgcn_mfma_f32_16x16x32_bf16(a, b, acc[n2], 0, 0, 0);
        }
    }
    const int lrow0 = rt * 16 + ((l >> 4) << 2);
#pragma unroll
    for (int n2 = 0; n2 < 4; n2++) {
        int col = (ch * 4 + n2) * 16 + (l & 15);
        float w0 = WpS[0][col], w1 = WpS[1][col], w2 = WpS[2][col];
#pragma unroll
        for (int r = 0; r < 4; r++) {
            int lr = lrow0 + r;
            int grow = rbase + lr;
            if (grow < N) {
                float v = acc[n2][r] + posS[lr][0] * w0 + posS[lr][1] * w1 + posS[lr][2] * w2;
                t[(size_t)grow * 128 + col] = f2bf(v);
            }
        }
    }
}

// ---------------- fused re-bin + gather + final GEMM + pos path (1024 threads) ----------------
__global__ __launch_bounds__(1024) void k_fused(const float* __restrict__ h,
                                                const float* __restrict__ pos,
                                                const float* __restrict__ nrm,
                                                const float* __restrict__ bhp,
                                                const unsigned short* __restrict__ t,
                                                const unsigned short* __restrict__ emb16,
                                                const int* __restrict__ gcnt,
                                                const unsigned* __restrict__ gbuf,
                                                const unsigned short* __restrict__ Wfrag,
                                                const float* __restrict__ Lwp,
                                                const float* __restrict__ Ewp,
                                                float* __restrict__ out, int N) {
    __shared__ unsigned eplists[32][CAP2];       // 6 KB
    __shared__ int lcnt2[32];
    __shared__ unsigned short x0sh[32][136];     // 8.5 KB
    __shared__ unsigned short hsh[32][136];      // 8.5 KB
    __shared__ float bsh[128];
    __shared__ float nrmS[32];
    const int tid = threadIdx.x;
    const int rbase = blockIdx.x * 32;
    const int w = tid >> 6, lane = tid & 63;
    const int half = lane >> 5;
    const int g = (lane >> 4) & 1, l16 = lane & 15;

    if (tid < 128) bsh[tid] = bhp[tid];
    if (tid < 32) {
        int row = rbase + tid;
        nrmS[tid] = (row < N) ? nrm[row] : 0.f;
        lcnt2[tid] = 0;
    }
    __syncthreads();

    // phase 0: re-bin this block's bucket into per-dst LDS lists
    const int cntB = min(gcnt[blockIdx.x], BS);
    for (int i = tid; i < cntB; i += 1024) {
        unsigned v = gbuf[(size_t)blockIdx.x * BS + i];
        int d = v & 31;
        int off = atomicAdd(&lcnt2[d], 1);
        if (off < CAP2) eplists[d][off] = v >> 5;   // src | type<<16
    }
    __syncthreads();

    const uint4* tw4 = reinterpret_cast<const uint4*>(t);      // row = 16 uint4
    const uint4* ew4 = reinterpret_cast<const uint4*>(emb16);

    // phase 1: 32 streams = 32 nodes, single pass (16 waves x 2 halves)
    {
        const int vl = w * 2 + half;                 // 0..31
        const int m = min(lcnt2[vl], CAP2);
        const int mm = max(min(lcnt2[w * 2], CAP2), min(lcnt2[w * 2 + 1], CAP2));  // wave-uniform
        float a[8];
#pragma unroll
        for (int r = 0; r < 8; r++) a[r] = 0.f;
        const unsigned* epr = &eplists[vl][0];
#pragma unroll 1
        for (int j = 0; j < mm; j += 8) {
            uint4 tv[4], ev[4];
            float sel[4];
#pragma unroll
            for (int u = 0; u < 4; u++) {
                int idx = j + 2 * u + g;
                unsigned pe = epr[min(idx, CAP2 - 1)];
                bool val = idx < m;
                unsigned pk = val ? pe : 0u;
                sel[u] = val ? 1.f : 0.f;
                tv[u] = tw4[(pk & 0xffffu) * 16u + l16];
                ev[u] = ew4[(pk >> 16) * 16u + l16];
            }
#pragma unroll
            for (int u = 0; u < 4; u++) {
                a[0] = fmaf(sel[u], bflo(tv[u].x) + bflo(ev[u].x), a[0]);
                a[1] = fmaf(sel[u], bfhi(tv[u].x) + bfhi(ev[u].x), a[1]);
                a[2] = fmaf(sel[u], bflo(tv[u].y) + bflo(ev[u].y), a[2]);
                a[3] = fmaf(sel[u], bfhi(tv[u].y) + bfhi(ev[u].y), a[3]);
                a[4] = fmaf(sel[u], bflo(tv[u].z) + bflo(ev[u].z), a[4]);
                a[5] = fmaf(sel[u], bfhi(tv[u].z) + bfhi(ev[u].z), a[5]);
                a[6] = fmaf(sel[u], bflo(tv[u].w) + bflo(ev[u].w), a[6]);
                a[7] = fmaf(sel[u], bfhi(tv[u].w) + bfhi(ev[u].w), a[7]);
            }
        }
        // cross-group reduce: group0 + group1
#pragma unroll
        for (int r = 0; r < 8; r++) a[r] += __shfl_xor(a[r], 16);
        if (g == 0) {
            float dg = (float)lcnt2[vl], nf = nrmS[vl];
            unsigned pk4[4];
#pragma unroll
            for (int q = 0; q < 4; q++) {
                float lo = nf * (a[2 * q]     + dg * bsh[l16 * 8 + 2 * q]);
                float hi = nf * (a[2 * q + 1] + dg * bsh[l16 * 8 + 2 * q + 1]);
                pk4[q] = (unsigned)f2bf(lo) | ((unsigned)f2bf(hi) << 16);
            }
            *reinterpret_cast<uint4*>(&x0sh[vl][l16 * 8]) =
                make_uint4(pk4[0], pk4[1], pk4[2], pk4[3]);
        }
    }

    // stage h tile as bf16 (exactly one float4 per thread)
    {
        int rr = tid >> 5, cq = tid & 31;
        int row = rbase + rr;
        float4 a = make_float4(0.f, 0.f, 0.f, 0.f);
        if (row < N)
            a = *reinterpret_cast<const float4*>(h + (size_t)row * 128 + cq * 4);
        u16x4 vv;
        vv[0] = f2bf(a.x); vv[1] = f2bf(a.y);
        vv[2] = f2bf(a.z); vv[3] = f2bf(a.w);
        *reinterpret_cast<u16x4*>(&hsh[rr][cq * 4]) = vv;
    }
    __syncthreads();

    // phase 2: out = relu([x0 | f*h | (1-f)*h] @ Wfrag); 16 waves = 2 row x 8 col tiles
    f32x4 acc = (f32x4){0.f, 0.f, 0.f, 0.f};
    const int rt = w & 1, ch = w >> 1;
    const int arow = rt * 16 + (lane & 15);
    const bool fl = (lcnt2[arow] > 0);
#pragma unroll
    for (int c = 0; c < 12; c++) {
        uint4 raw;
        if (c < 4) {
            raw = *reinterpret_cast<const uint4*>(&x0sh[arow][c * 32 + (lane >> 4) * 8]);
        } else {
            raw = *reinterpret_cast<const uint4*>(&hsh[arow][(c & 3) * 32 + (lane >> 4) * 8]);
            bool keep = (c < 8) ? fl : !fl;
            if (!keep) { raw.x = 0; raw.y = 0; raw.z = 0; raw.w = 0; }
        }
        bf16x8 a = *reinterpret_cast<bf16x8*>(&raw);
        bf16x8 b = (reinterpret_cast<const bf16x8*>(Wfrag) + (size_t)c * 512)[ch * 64 + lane];
        acc = __builtin_amdgcn_mfma_f32_16x16x32_bf16(a, b, acc, 0, 0, 0);
    }
    {
        const int lrow0 = rt * 16 + ((lane >> 4) << 2);
        int col = ch * 16 + (lane & 15);
#pragma unroll
        for (int r = 0; r < 4; r++) {
            int grow = rbase + lrow0 + r;
            if (grow < N)
                out[(size_t)grow * 128 + col] = fmaxf(acc[r], 0.f);
        }
    }
    // pos path
    if (tid < 32) {
        int row = rbase + tid;
        if (row < N) {
            float p0 = pos[(size_t)row * 3 + 0];
            float p1 = pos[(size_t)row * 3 + 1];
            float p2 = pos[(size_t)row * 3 + 2];
            const float* M = (lcnt2[tid] > 0) ? Lwp : Ewp;
            float o0 = p0 + (p0 * M[0] + p1 * M[3] + p2 * M[6]);
            float o1 = p1 + (p0 * M[1] + p1 * M[4] + p2 * M[7]);
            float o2 = p2 + (p0 * M[2] + p1 * M[5] + p2 * M[8]);
            size_t base = (size_t)N * 128 + (size_t)row * 3;
            out[base + 0] = fmaxf(o0, 0.f);
            out[base + 1] = fmaxf(o1, 0.f);
            out[base + 2] = fmaxf(o2, 0.f);
        }
    }
}

extern "C" void kernel_launch(void* const* d_in, const int* in_sizes, int n_in,
                              void* d_out, int out_size, void* d_ws, size_t ws_size,
                              hipStream_t stream) {
    const float* h   = (const float*)d_in[0];
    const float* pos = (const float*)d_in[1];
    const float* nrm = (const float*)d_in[2];
    const float* emb = (const float*)d_in[3];
    const float* Whp = (const float*)d_in[4];
    const float* bhp = (const float*)d_in[5];
    const float* Wn  = (const float*)d_in[6];
    const float* Lw  = (const float*)d_in[7];
    const float* Ew  = (const float*)d_in[8];
    const float* Lwp = (const float*)d_in[9];
    const float* Ewp = (const float*)d_in[10];
    const int* esrc  = (const int*)d_in[11];
    const int* edst  = (const int*)d_in[12];
    const int* etyp  = (const int*)d_in[13];

    const int N = in_sizes[2];
    const int E = in_sizes[11];
    const int embN = in_sizes[3];

    float* out = (float*)d_out;

    char* wsb = (char*)d_ws;
    size_t off = 0;
    auto nalloc = [&](size_t bytes) { char* p = wsb + off; off += (bytes + 255) & ~(size_t)255; return p; };
    const int nbkt = (N + 31) / 32;
    unsigned short* t       = (unsigned short*)nalloc((size_t)N * 128 * 2);
    int*            gcnt    = (int*)nalloc((size_t)nbkt * 4);
    unsigned*       gbuf    = (unsigned*)nalloc((size_t)nbkt * BS * 4);
    unsigned short* emb16   = (unsigned short*)nalloc((size_t)embN * 2);
    unsigned short* Wfrag   = (unsigned short*)nalloc(49152 * 2);
    unsigned short* Whpfrag = (unsigned short*)nalloc(16384 * 2);

    k_pack<<<64, 256, 0, stream>>>(Whp, gcnt, Whpfrag, nbkt);
    const int nTB = (N + 63) / 64;
    const int nBB = (E + CH - 1) / CH;
    const int nPB = 32;
    k_comb<<<nBB + nPB + nTB, 512, 0, stream>>>(h, pos, Whp, Whpfrag, t,
                                                esrc, edst, etyp, E,
                                                gcnt, gbuf,
                                                emb, embN, Wn, Lw, Ew,
                                                emb16, Wfrag, nBB, nPB, nbkt, N);
    k_fused<<<nbkt, 1024, 0, stream>>>(h, pos, nrm, bhp, t, emb16, gcnt, gbuf,
                                       Wfrag, Lwp, Ewp, out, N);
}

// Round 12
// 64.951 us; speedup vs baseline: 1.1430x; 1.1430x over previous
//
#include <hip/hip_runtime.h>

// UnionRGCNLayer, fused MFMA version (K=256 fast path + rare deg-0 patch):
//   k_pack: zero gcnt + pack Whp into MFMA fragment order
//   k_comb: blocks [0,nBB):        bin 8k edges each into per-dst-block buckets
//           blocks [nBB,nBB+nPB):  pack [Wn;Lw]->Wfrag, emb->emb16
//           blocks [nBB+nPB,..):   t = [h|pos] @ W_hp (bf16 MFMA, M=64) + emit h16
//   k_fused per 32-row block (512 thr):
//     phase0: read own bucket (coalesced), re-bin to per-dst LDS lists (LDS atomics)
//     phase1: x0[v] = norm*(sum_edges(t[src]+emb[type]) + deg*b) -> LDS bf16
//             16-lane groups, uint4 row loads, sel-masked uniform control flow
//     phase2: out = relu([x0 | h] @ [Wn;Lw]) (deg>0 rows; x0=0 when deg=0 so no mask);
//             rows with deg==0 (Poisson(16): ~e^-16, ~never) get exact fp32 patch
//             out = relu(h @ Ew) and skip the MFMA store
//     pos:    out_pos = relu(pos + pos @ (deg>0 ? Lwp : Ewp))
// MFMA packing convention (consistent A/B; k-permutation cancels):
//   A: lane l elem j -> A[l&15][(l>>4)*8+j];  B: lane l elem j -> B[(l>>4)*8+j][l&15]
//   C/D (m89-verified): lane l reg r -> D[(l>>4)*4+r][l&15]

#define BS 1536        // bucket capacity (mean 512, 22 sigma headroom)
#define CAP2 48        // per-dst list cap (Poisson(16): P(>48) ~ 1e-12)
#define CH 8192        // edges per bin block

typedef __bf16 bf16x8 __attribute__((ext_vector_type(8)));
typedef float f32x4 __attribute__((ext_vector_type(4)));
typedef unsigned short u16x4 __attribute__((ext_vector_type(4)));

__device__ inline unsigned short f2bf(float f) {
    unsigned u = __float_as_uint(f);
    u += 0x7fffu + ((u >> 16) & 1u);
    return (unsigned short)(u >> 16);
}
__device__ inline float bflo(unsigned u) { return __uint_as_float(u << 16); }
__device__ inline float bfhi(unsigned u) { return __uint_as_float(u & 0xffff0000u); }

// ---------------- k_pack: zero gcnt + Whp fragment packing ----------------
__global__ __launch_bounds__(256) void k_pack(const float* __restrict__ Whp,
                                              int* __restrict__ gcnt,
                                              unsigned short* __restrict__ Whpfrag,
                                              int nbkt) {
    const int gid = blockIdx.x * blockDim.x + threadIdx.x;
    const int gs = gridDim.x * blockDim.x;
    for (int i = gid; i < nbkt; i += gs) gcnt[i] = 0;
    for (int i = gid; i < 16384; i += gs) {  // Whp rows 0..127 -> fragment order
        int j = i & 7, l = (i >> 3) & 63, nt = (i >> 9) & 7, c = i >> 12;
        int k = c * 32 + ((l >> 4) << 3) + j;
        int n = nt * 16 + (l & 15);
        Whpfrag[i] = f2bf(Whp[k * 128 + n]);
    }
}

// ---------------- k_comb: bin (first) + pack + t-GEMM (M=64, emits h16) ----------------
__global__ __launch_bounds__(512) void k_comb(const float* __restrict__ h,
                                              const float* __restrict__ pos,
                                              const float* __restrict__ Whp,
                                              const unsigned short* __restrict__ Whpfrag,
                                              unsigned short* __restrict__ t,
                                              unsigned short* __restrict__ h16,
                                              const int* __restrict__ esrc,
                                              const int* __restrict__ edst,
                                              const int* __restrict__ etyp, int E,
                                              int* __restrict__ gcnt,
                                              unsigned* __restrict__ gbuf,
                                              const float* __restrict__ emb, int embN,
                                              const float* __restrict__ Wn,
                                              const float* __restrict__ Lw,
                                              unsigned short* __restrict__ emb16,
                                              unsigned short* __restrict__ Wfrag,
                                              int nBB, int nPB,
                                              int nbkt, int N) {
    __shared__ unsigned short hsh[64][136];   // GEMM tile; aliased by bin path
    __shared__ float WpS[3][128];
    __shared__ float posS[64][4];
    const int tid = threadIdx.x;

    if (blockIdx.x < nBB) {
        // ---- bin block: two-pass LDS-count binning of CH edges, int4-vectorized ----
        int* lcnt = reinterpret_cast<int*>(&hsh[0][0]);   // nbkt ints
        int* lbase = lcnt + 1280;                         // nbkt ints
        const int e0 = blockIdx.x * CH;
        const int eN = min(E - e0, CH);
        for (int i = tid; i < nbkt; i += 512) lcnt[i] = 0;
        __syncthreads();
        // pass A: histogram (4 edges per thread per sweep)
        for (int base = tid * 4; base < eN; base += 2048) {
            if (base + 3 < eN) {
                int4 d4 = *reinterpret_cast<const int4*>(&edst[e0 + base]);
                atomicAdd(&lcnt[d4.x >> 5], 1);
                atomicAdd(&lcnt[d4.y >> 5], 1);
                atomicAdd(&lcnt[d4.z >> 5], 1);
                atomicAdd(&lcnt[d4.w >> 5], 1);
            } else {
                for (int k = 0; k < 4 && base + k < eN; k++)
                    atomicAdd(&lcnt[edst[e0 + base + k] >> 5], 1);
            }
        }
        __syncthreads();
        // reserve contiguous runs: 1 global atomic per (bucket,block)
        for (int i = tid; i < nbkt; i += 512) {
            int c = lcnt[i];
            lbase[i] = c ? atomicAdd(&gcnt[i], c) : 0;
        }
        __syncthreads();
        for (int i = tid; i < nbkt; i += 512) lcnt[i] = 0;
        __syncthreads();
        // pass B: write runs
        for (int base = tid * 4; base < eN; base += 2048) {
            if (base + 3 < eN) {
                int4 d4 = *reinterpret_cast<const int4*>(&edst[e0 + base]);
                int4 s4 = *reinterpret_cast<const int4*>(&esrc[e0 + base]);
                int4 t4 = *reinterpret_cast<const int4*>(&etyp[e0 + base]);
                int dd[4] = {d4.x, d4.y, d4.z, d4.w};
                int ss[4] = {s4.x, s4.y, s4.z, s4.w};
                int tt[4] = {t4.x, t4.y, t4.z, t4.w};
#pragma unroll
                for (int k = 0; k < 4; k++) {
                    int b = dd[k] >> 5;
                    unsigned val = (unsigned)(dd[k] & 31) | ((unsigned)ss[k] << 5)
                                 | ((unsigned)tt[k] << 21);
                    int off = atomicAdd(&lcnt[b], 1);
                    gbuf[(size_t)b * BS + min(lbase[b] + off, BS - 1)] = val;
                }
            } else {
                for (int k = 0; k < 4 && base + k < eN; k++) {
                    int d = edst[e0 + base + k];
                    int b = d >> 5;
                    unsigned val = (unsigned)(d & 31) | ((unsigned)esrc[e0 + base + k] << 5)
                                 | ((unsigned)etyp[e0 + base + k] << 21);
                    int off = atomicAdd(&lcnt[b], 1);
                    gbuf[(size_t)b * BS + min(lbase[b] + off, BS - 1)] = val;
                }
            }
        }
        return;
    }

    if (blockIdx.x < nBB + nPB) {
        // packing blocks: Wfrag [Wn;Lw] + emb16 (consumed only by k_fused)
        const int base = (blockIdx.x - nBB) * 512 + tid;
        const int gs = nPB * 512;
        for (int i = base; i < 32768; i += gs) {
            int j = i & 7, l = (i >> 3) & 63, nt = (i >> 9) & 7, c = i >> 12;
            int k = c * 32 + ((l >> 4) << 3) + j;
            int n = nt * 16 + (l & 15);
            float v = (k < 128) ? Wn[k * 128 + n] : Lw[(k - 128) * 128 + n];
            Wfrag[i] = f2bf(v);
        }
        for (int i = base; i < embN; i += gs) emb16[i] = f2bf(emb[i]);
        return;
    }

    // ---- t-GEMM block ----
    const int rbase = (blockIdx.x - nBB - nPB) * 64;
    const int w = tid >> 6, l = tid & 63;
    for (int i = tid; i < 384; i += 512) WpS[i >> 7][i & 127] = Whp[128 * 128 + i];
    if (tid < 192) {
        int r = tid / 3, j = tid % 3;
        int row = rbase + r;
        posS[r][j] = (row < N) ? pos[(size_t)row * 3 + j] : 0.f;
    }
#pragma unroll
    for (int it = 0; it < 4; it++) {  // stage 64x128 h tile as bf16 (+ emit h16)
        int qid = tid + it * 512;
        int rr = qid >> 5, cq = qid & 31;
        int row = rbase + rr;
        u16x4 v = {0, 0, 0, 0};
        if (row < N) {
            float4 a = *reinterpret_cast<const float4*>(h + (size_t)row * 128 + cq * 4);
            v[0] = f2bf(a.x); v[1] = f2bf(a.y); v[2] = f2bf(a.z); v[3] = f2bf(a.w);
            *reinterpret_cast<u16x4*>(&h16[(size_t)row * 128 + cq * 4]) = v;
        }
        *reinterpret_cast<u16x4*>(&hsh[rr][cq * 4]) = v;
    }
    __syncthreads();

    f32x4 acc[4];
#pragma unroll
    for (int i = 0; i < 4; i++) acc[i] = (f32x4){0.f, 0.f, 0.f, 0.f};
    const int rt = w >> 1, ch = w & 1;   // 4 row-tiles x 2 col-halves
#pragma unroll
    for (int c = 0; c < 4; c++) {
        bf16x8 a = *reinterpret_cast<const bf16x8*>(&hsh[rt * 16 + (l & 15)][c * 32 + (l >> 4) * 8]);
        const bf16x8* Bp = reinterpret_cast<const bf16x8*>(Whpfrag) + (size_t)c * 512;
#pragma unroll
        for (int n2 = 0; n2 < 4; n2++) {
            bf16x8 b = Bp[(ch * 4 + n2) * 64 + l];
            acc[n2] = __builtin_amdgcn_mfma_f32_16x16x32_bf16(a, b, acc[n2], 0, 0, 0);
        }
    }
    const int lrow0 = rt * 16 + ((l >> 4) << 2);
#pragma unroll
    for (int n2 = 0; n2 < 4; n2++) {
        int col = (ch * 4 + n2) * 16 + (l & 15);
        float w0 = WpS[0][col], w1 = WpS[1][col], w2 = WpS[2][col];
#pragma unroll
        for (int r = 0; r < 4; r++) {
            int lr = lrow0 + r;
            int grow = rbase + lr;
            if (grow < N) {
                float v = acc[n2][r] + posS[lr][0] * w0 + posS[lr][1] * w1 + posS[lr][2] * w2;
                t[(size_t)grow * 128 + col] = f2bf(v);
            }
        }
    }
}

// ---------------- fused re-bin + gather + final GEMM + pos path (512 threads) ----------------
__global__ __launch_bounds__(512) void k_fused(const float* __restrict__ h,
                                               const float* __restrict__ pos,
                                               const float* __restrict__ nrm,
                                               const float* __restrict__ bhp,
                                               const unsigned short* __restrict__ t,
                                               const unsigned short* __restrict__ h16,
                                               const unsigned short* __restrict__ emb16,
                                               const int* __restrict__ gcnt,
                                               const unsigned* __restrict__ gbuf,
                                               const unsigned short* __restrict__ Wfrag,
                                               const float* __restrict__ Ew,
                                               const float* __restrict__ Lwp,
                                               const float* __restrict__ Ewp,
                                               float* __restrict__ out, int N) {
    __shared__ unsigned eplists[32][CAP2];       // 6 KB
    __shared__ int lcnt2[32];
    __shared__ unsigned short x0sh[32][136];     // 8.5 KB
    __shared__ unsigned short hsh[32][136];      // 8.5 KB
    __shared__ float bsh[128];
    __shared__ float nrmS[32];
    __shared__ int zrowsS[32];
    __shared__ int nzS;
    const int tid = threadIdx.x;
    const int rbase = blockIdx.x * 32;
    const int w = tid >> 6, lane = tid & 63;
    const int half = lane >> 5;
    const int g = (lane >> 4) & 1, l16 = lane & 15;

    if (tid < 128) bsh[tid] = bhp[tid];
    if (tid == 128) nzS = 0;
    if (tid < 32) {
        int row = rbase + tid;
        nrmS[tid] = (row < N) ? nrm[row] : 0.f;
        lcnt2[tid] = 0;
    }
    __syncthreads();

    // phase 0: re-bin this block's bucket into per-dst LDS lists
    const int cntB = min(gcnt[blockIdx.x], BS);
    for (int i = tid; i < cntB; i += 512) {
        unsigned v = gbuf[(size_t)blockIdx.x * BS + i];
        int d = v & 31;
        int off = atomicAdd(&lcnt2[d], 1);
        if (off < CAP2) eplists[d][off] = v >> 5;   // src | type<<16
    }
    __syncthreads();

    // collect rare deg==0 rows (expected ~never: P ~ e^-16)
    if (tid < 32) {
        int row = rbase + tid;
        if (row < N && lcnt2[tid] == 0) {
            int o = atomicAdd(&nzS, 1);
            zrowsS[o] = tid;
        }
    }

    const uint4* tw4 = reinterpret_cast<const uint4*>(t);      // row = 16 uint4
    const uint4* ew4 = reinterpret_cast<const uint4*>(emb16);

    // phase 1: per wave-half one node per pass; 16-lane groups take alternating slots
#pragma unroll 1
    for (int p = 0; p < 2; p++) {
        const int base2 = p * 16 + w * 2;
        const int vl = base2 + half;
        const int m = min(lcnt2[vl], CAP2);
        const int mm = max(min(lcnt2[base2], CAP2), min(lcnt2[base2 + 1], CAP2));  // wave-uniform
        float a[8];
#pragma unroll
        for (int r = 0; r < 8; r++) a[r] = 0.f;
        const unsigned* epr = &eplists[vl][0];
#pragma unroll 1
        for (int j = 0; j < mm; j += 8) {
            uint4 tv[4], ev[4];
            float sel[4];
#pragma unroll
            for (int u = 0; u < 4; u++) {
                int idx = j + 2 * u + g;
                unsigned pe = epr[min(idx, CAP2 - 1)];
                bool val = idx < m;
                unsigned pk = val ? pe : 0u;
                sel[u] = val ? 1.f : 0.f;
                tv[u] = tw4[(pk & 0xffffu) * 16u + l16];
                ev[u] = ew4[(pk >> 16) * 16u + l16];
            }
#pragma unroll
            for (int u = 0; u < 4; u++) {
                a[0] = fmaf(sel[u], bflo(tv[u].x) + bflo(ev[u].x), a[0]);
                a[1] = fmaf(sel[u], bfhi(tv[u].x) + bfhi(ev[u].x), a[1]);
                a[2] = fmaf(sel[u], bflo(tv[u].y) + bflo(ev[u].y), a[2]);
                a[3] = fmaf(sel[u], bfhi(tv[u].y) + bfhi(ev[u].y), a[3]);
                a[4] = fmaf(sel[u], bflo(tv[u].z) + bflo(ev[u].z), a[4]);
                a[5] = fmaf(sel[u], bfhi(tv[u].z) + bfhi(ev[u].z), a[5]);
                a[6] = fmaf(sel[u], bflo(tv[u].w) + bflo(ev[u].w), a[6]);
                a[7] = fmaf(sel[u], bfhi(tv[u].w) + bfhi(ev[u].w), a[7]);
            }
        }
        // cross-group reduce: group0 + group1
#pragma unroll
        for (int r = 0; r < 8; r++) a[r] += __shfl_xor(a[r], 16);
        if (g == 0) {
            float dg = (float)lcnt2[vl], nf = nrmS[vl];
            unsigned pk4[4];
#pragma unroll
            for (int q = 0; q < 4; q++) {
                float lo = nf * (a[2 * q]     + dg * bsh[l16 * 8 + 2 * q]);
                float hi = nf * (a[2 * q + 1] + dg * bsh[l16 * 8 + 2 * q + 1]);
                pk4[q] = (unsigned)f2bf(lo) | ((unsigned)f2bf(hi) << 16);
            }
            *reinterpret_cast<uint4*>(&x0sh[vl][l16 * 8]) =
                make_uint4(pk4[0], pk4[1], pk4[2], pk4[3]);
        }
    }

    // stage h tile from h16 (exactly one uint4 per thread)
    {
        int rr = tid >> 4, q = tid & 15;
        int row = rbase + rr;
        uint4 v = make_uint4(0, 0, 0, 0);
        if (row < N)
            v = reinterpret_cast<const uint4*>(h16)[(size_t)row * 16 + q];
        *reinterpret_cast<uint4*>(&hsh[rr][q * 8]) = v;
    }
    __syncthreads();

    // phase 2: out = relu([x0 | h] @ [Wn;Lw]); 8 waves = 2 row x 4 col tiles, K=256
    f32x4 acc[2];
    acc[0] = (f32x4){0.f, 0.f, 0.f, 0.f};
    acc[1] = (f32x4){0.f, 0.f, 0.f, 0.f};
    const int rt = w >> 2, ch = w & 3;
    const int arow = rt * 16 + (lane & 15);
#pragma unroll
    for (int c = 0; c < 8; c++) {
        uint4 raw;
        if (c < 4)
            raw = *reinterpret_cast<const uint4*>(&x0sh[arow][c * 32 + (lane >> 4) * 8]);
        else
            raw = *reinterpret_cast<const uint4*>(&hsh[arow][(c & 3) * 32 + (lane >> 4) * 8]);
        bf16x8 a = *reinterpret_cast<bf16x8*>(&raw);
        const bf16x8* Bp = reinterpret_cast<const bf16x8*>(Wfrag) + (size_t)c * 512;
#pragma unroll
        for (int n2 = 0; n2 < 2; n2++) {
            bf16x8 b = Bp[(ch * 2 + n2) * 64 + lane];
            acc[n2] = __builtin_amdgcn_mfma_f32_16x16x32_bf16(a, b, acc[n2], 0, 0, 0);
        }
    }
    const int lrow0 = rt * 16 + ((lane >> 4) << 2);
#pragma unroll
    for (int n2 = 0; n2 < 2; n2++) {
        int col = (ch * 2 + n2) * 16 + (lane & 15);
#pragma unroll
        for (int r = 0; r < 4; r++) {
            int lr = lrow0 + r;
            int grow = rbase + lr;
            if (grow < N && lcnt2[lr] > 0)
                out[(size_t)grow * 128 + col] = fmaxf(acc[n2][r], 0.f);
        }
    }
    // rare deg==0 patch: out = relu(h @ Ew), exact fp32 (block-uniform loop, ~never runs)
    for (int zi = 0; zi < nzS; zi++) {
        int r = zrowsS[zi];
        int row = rbase + r;
        if (tid < 128) {
            float accp = 0.f;
            for (int k = 0; k < 128; k++)
                accp += h[(size_t)row * 128 + k] * Ew[k * 128 + tid];
            out[(size_t)row * 128 + tid] = fmaxf(accp, 0.f);
        }
    }
    // pos path
    if (tid < 32) {
        int row = rbase + tid;
        if (row < N) {
            float p0 = pos[(size_t)row * 3 + 0];
            float p1 = pos[(size_t)row * 3 + 1];
            float p2 = pos[(size_t)row * 3 + 2];
            const float* M = (lcnt2[tid] > 0) ? Lwp : Ewp;
            float o0 = p0 + (p0 * M[0] + p1 * M[3] + p2 * M[6]);
            float o1 = p1 + (p0 * M[1] + p1 * M[4] + p2 * M[7]);
            float o2 = p2 + (p0 * M[2] + p1 * M[5] + p2 * M[8]);
            size_t base = (size_t)N * 128 + (size_t)row * 3;
            out[base + 0] = fmaxf(o0, 0.f);
            out[base + 1] = fmaxf(o1, 0.f);
            out[base + 2] = fmaxf(o2, 0.f);
        }
    }
}

extern "C" void kernel_launch(void* const* d_in, const int* in_sizes, int n_in,
                              void* d_out, int out_size, void* d_ws, size_t ws_size,
                              hipStream_t stream) {
    const float* h   = (const float*)d_in[0];
    const float* pos = (const float*)d_in[1];
    const float* nrm = (const float*)d_in[2];
    const float* emb = (const float*)d_in[3];
    const float* Whp = (const float*)d_in[4];
    const float* bhp = (const float*)d_in[5];
    const float* Wn  = (const float*)d_in[6];
    const float* Lw  = (const float*)d_in[7];
    const float* Ew  = (const float*)d_in[8];
    const float* Lwp = (const float*)d_in[9];
    const float* Ewp = (const float*)d_in[10];
    const int* esrc  = (const int*)d_in[11];
    const int* edst  = (const int*)d_in[12];
    const int* etyp  = (const int*)d_in[13];

    const int N = in_sizes[2];
    const int E = in_sizes[11];
    const int embN = in_sizes[3];

    float* out = (float*)d_out;

    char* wsb = (char*)d_ws;
    size_t off = 0;
    auto nalloc = [&](size_t bytes) { char* p = wsb + off; off += (bytes + 255) & ~(size_t)255; return p; };
    const int nbkt = (N + 31) / 32;
    unsigned short* t       = (unsigned short*)nalloc((size_t)N * 128 * 2);
    unsigned short* h16     = (unsigned short*)nalloc((size_t)N * 128 * 2);
    int*            gcnt    = (int*)nalloc((size_t)nbkt * 4);
    unsigned*       gbuf    = (unsigned*)nalloc((size_t)nbkt * BS * 4);
    unsigned short* emb16   = (unsigned short*)nalloc((size_t)embN * 2);
    unsigned short* Wfrag   = (unsigned short*)nalloc(32768 * 2);
    unsigned short* Whpfrag = (unsigned short*)nalloc(16384 * 2);

    k_pack<<<64, 256, 0, stream>>>(Whp, gcnt, Whpfrag, nbkt);
    const int nTB = (N + 63) / 64;
    const int nBB = (E + CH - 1) / CH;
    const int nPB = 32;
    k_comb<<<nBB + nPB + nTB, 512, 0, stream>>>(h, pos, Whp, Whpfrag, t, h16,
                                                esrc, edst, etyp, E,
                                                gcnt, gbuf,
                                                emb, embN, Wn, Lw,
                                                emb16, Wfrag, nBB, nPB, nbkt, N);
    k_fused<<<nbkt, 512, 0, stream>>>(h, pos, nrm, bhp, t, h16, emb16, gcnt, gbuf,
                                      Wfrag, Ew, Lwp, Ewp, out, N);
}